// Round 10
// baseline (33.604 us; speedup 1.0000x reference)
//
#include <hip/hip_runtime.h>

// SIMcLoss: x [8192, 256] fp32 -> scalar.
// loss = (||Xn^T Xn||_F^2 - n)/(n^2 - n) on the 256x256 Gram matrix.
// Three dispatches (dispatch boundaries proved CHEAPER than any in-kernel
// cross-block hand-off in rounds 6-9):
//   k_norm_t : normalize rows (bf16 RNE) ONCE and store TRANSPOSED
//              XnT[256][8192] (4 MB) -> gram needs no LDS/barriers/VALU.
//   k_gram   : pure-MFMA Gram tiles; frags loaded straight from global
//              (L2-resident); 10 sym pairs x 32 K-chunks = 320 blocks.
//   k_reduce : per-element chunk-sum, weight, square, 160 S-atomics,
//              last-block ticket writes the loss.
#define D 256
#define TILE 64
#define NPAIRS 10
#define CHUNK 256
#define NCHUNK 32
#define RPB 32            // rows per k_norm_t block
#define EPS 1e-8f

typedef __attribute__((ext_vector_type(8))) short bf16x8;
typedef __attribute__((ext_vector_type(8))) unsigned short u16x8;
typedef __attribute__((ext_vector_type(4))) float f32x4;

__device__ __forceinline__ void pair_decode(int p, int& ta, int& tb) {
  if (p < 4)      { ta = 0; tb = p; }
  else if (p < 7) { ta = 1; tb = p - 3; }
  else if (p < 9) { ta = 2; tb = p - 5; }
  else            { ta = 3; tb = 3; }
}

// round-to-nearest-even fp32 -> bf16 (truncation would bias S)
__device__ __forceinline__ unsigned short rne_bf16(float f) {
  unsigned u = __float_as_uint(f);
  return (unsigned short)((u + 0x7fffu + ((u >> 16) & 1u)) >> 16);
}

// ---------------------------------------------------------------------------
// Kernel 1: norms + bf16 convert + transpose. 256 blocks x 256 thr.
// Block handles RPB=32 rows: wave per row (butterfly norm, all lanes hold s),
// bf16 into LDS [32][260] (padded), then col-threads write 64 B contiguous
// runs of XnT. Also zeroes ctrl words (block 0).
// ---------------------------------------------------------------------------
__global__ __launch_bounds__(256) void k_norm_t(
    const float* __restrict__ x, unsigned short* __restrict__ xt,
    float* __restrict__ ctrl, int N) {
  if (blockIdx.x == 0 && threadIdx.x < 16) ctrl[threadIdx.x] = 0.0f;
  const int tid = threadIdx.x;
  const int w = tid >> 6, lane = tid & 63;
  const int row0 = blockIdx.x * RPB;

  __shared__ unsigned short T[RPB][260];   // pad 260: conflict-free phases

  #pragma unroll
  for (int it = 0; it < RPB / 4; ++it) {
    const int r = it * 4 + w;
    const float4 v = reinterpret_cast<const float4*>(
        x + (size_t)(row0 + r) * D)[lane];
    float s = v.x * v.x + v.y * v.y + v.z * v.z + v.w * v.w;
    #pragma unroll
    for (int o = 32; o > 0; o >>= 1) s += __shfl_xor(s, o);
    const float iv = 1.0f / fmaxf(sqrtf(s), EPS);
    *reinterpret_cast<ushort4*>(&T[r][lane * 4]) =
        make_ushort4(rne_bf16(v.x * iv), rne_bf16(v.y * iv),
                     rne_bf16(v.z * iv), rne_bf16(v.w * iv));
  }
  __syncthreads();

  // thread tid = column; write XnT[tid][row0..row0+31] (64 B contiguous)
  #pragma unroll
  for (int g = 0; g < RPB / 8; ++g) {
    u16x8 o;
    #pragma unroll
    for (int rr = 0; rr < 8; ++rr) o[rr] = T[g * 8 + rr][tid];
    *reinterpret_cast<u16x8*>(&xt[(size_t)tid * N + row0 + g * 8]) = o;
  }
}

// ---------------------------------------------------------------------------
// Kernel 2: pure-MFMA Gram tiles. grid (NPAIRS, NCHUNK), 512 threads.
// Wave w owns a 16x32 quadrant; fragments come straight from XnT (global,
// L2-resident; 16 B contiguous per lane, 4 lanes/line). No LDS, no barriers.
// ---------------------------------------------------------------------------
__global__ __launch_bounds__(512) void k_gram(
    const unsigned short* __restrict__ xt, float* __restrict__ slabs, int N) {
  int ta, tb; pair_decode(blockIdx.x, ta, tb);
  const int row0 = blockIdx.y * CHUNK;
  const int tid = threadIdx.x;
  const int w = tid >> 6, lane = tid & 63;
  const int i0 = (w >> 1) << 4;                 // 0,16,32,48
  const int j0 = (w & 1) << 5;                  // 0,32
  const int lm = lane & 15, lk = lane >> 4;

  const unsigned short* pA  = xt + (size_t)(ta * TILE + i0 + lm) * N + row0;
  const unsigned short* pB0 = xt + (size_t)(tb * TILE + j0 + lm) * N + row0;
  const unsigned short* pB1 = pB0 + (size_t)16 * N;

  f32x4 zero = {0.f, 0.f, 0.f, 0.f};
  f32x4 acc[2] = {zero, zero};

  #pragma unroll
  for (int ks = 0; ks < CHUNK; ks += 32) {
    const int rb = ks + lk * 8;
    bf16x8 A  = *reinterpret_cast<const bf16x8*>(pA + rb);
    bf16x8 B0 = *reinterpret_cast<const bf16x8*>(pB0 + rb);
    bf16x8 B1 = *reinterpret_cast<const bf16x8*>(pB1 + rb);
    acc[0] = __builtin_amdgcn_mfma_f32_16x16x32_bf16(A, B0, acc[0], 0, 0, 0);
    acc[1] = __builtin_amdgcn_mfma_f32_16x16x32_bf16(A, B1, acc[1], 0, 0, 0);
  }

  // slab store; C/D layout (m89): col = lane&15, row = (lane>>4)*4 + reg
  float* slab = slabs +
      ((size_t)blockIdx.x * NCHUNK + blockIdx.y) * (TILE * TILE);
  #pragma unroll
  for (int jt = 0; jt < 2; ++jt)
    #pragma unroll
    for (int rg = 0; rg < 4; ++rg)
      slab[(i0 + lk * 4 + rg) * TILE + (j0 + jt * 16 + lm)] = acc[jt][rg];
}

// ---------------------------------------------------------------------------
// Kernel 3: reduce. 160 blocks x 256 threads; one G element per thread:
// sum NCHUNK slab partials (coalesced), weight, square, block-reduce,
// atomicAdd(S) per block, last-block ticket writes the loss.
// ---------------------------------------------------------------------------
__global__ __launch_bounds__(256) void k_reduce(
    const float* __restrict__ slabs, float* __restrict__ S,
    unsigned int* __restrict__ cnt, float* __restrict__ out,
    int N, int nblocks) {
  const int g = blockIdx.x * 256 + threadIdx.x;
  const int p = g >> 12;                        // pair 0..9
  const int e = g & 4095;                       // element in 64x64 tile
  const float* base = slabs + (size_t)p * NCHUNK * (TILE * TILE) + e;
  float tot = 0.f;
  #pragma unroll
  for (int c = 0; c < NCHUNK; ++c) tot += base[(size_t)c * (TILE * TILE)];
  const bool diag = (p == 0) | (p == 4) | (p == 7) | (p == 9);
  float part = (diag ? 1.f : 2.f) * tot * tot;
  #pragma unroll
  for (int o = 32; o > 0; o >>= 1) part += __shfl_xor(part, o);
  __shared__ float red[4];
  int lane = threadIdx.x & 63, w = threadIdx.x >> 6;
  if (lane == 0) red[w] = part;
  __syncthreads();
  if (threadIdx.x == 0) {
    float blk = red[0] + red[1] + red[2] + red[3];
    atomicAdd(S, blk);
    __threadfence();
    unsigned int old = atomicAdd(cnt, 1u);
    if (old == (unsigned int)(nblocks - 1)) {
      float Sv = __hip_atomic_load(S, __ATOMIC_RELAXED,
                                   __HIP_MEMORY_SCOPE_AGENT);
      float nf = (float)N;
      out[0] = (Sv - nf) / (nf * nf - nf);
    }
  }
}

extern "C" void kernel_launch(void* const* d_in, const int* in_sizes, int n_in,
                              void* d_out, int out_size, void* d_ws, size_t ws_size,
                              hipStream_t stream) {
  const float* x = (const float*)d_in[0];
  float* out = (float*)d_out;
  const int N = in_sizes[0] / D;       // 8192

  // ws layout (floats): ctrl[64] (S, cnt) | XnT[D*N bf16 = D*N/2 floats] | slabs
  float* ctrl = (float*)d_ws;
  float* S = ctrl;
  unsigned int* cnt = (unsigned int*)(ctrl + 1);
  unsigned short* xt = (unsigned short*)(ctrl + 64);
  float* slabs = ctrl + 64 + (size_t)D * N / 2;

  k_norm_t<<<dim3(N / RPB), dim3(256), 0, stream>>>(x, xt, ctrl, N);
  k_gram<<<dim3(NPAIRS, NCHUNK), dim3(512), 0, stream>>>(xt, slabs, N);
  const int nb = NPAIRS * (TILE * TILE / 256);  // 160
  k_reduce<<<dim3(nb), dim3(256), 0, stream>>>(slabs, S, cnt, out, N, nb);
}

// Round 12
// 26.454 us; speedup vs baseline: 1.2703x; 1.2703x over previous
//
#include <hip/hip_runtime.h>

// SIMcLoss: x [8192, 256] fp32 -> scalar.
// loss = (||Xn^T Xn||_F^2 - n)/(n^2 - n) on the 256x256 Gram matrix.
// Three dispatches (best-known structure, round 5; fusion attempts all
// regressed in rounds 6-10):
//   k_prep   : one wave per row -> inv norms; zeroes ctrl words.
//   k_gram   : bf16(RNE) MFMA Gram tiles, WORK-BALANCED grid: 6 off-diag
//              pairs x 32 chunks (256 rows) + 4 diag pairs x 16 chunks
//              (512 rows) = 256 blocks, 1/CU, equal staging per block.
//              Double-buffered LDS, 1 barrier/sub-chunk, slab store.
//   k_reduce : per-element partial-sum (32 or 16 chunks), weight, square,
//              block reduce, 160 S-atomics, last-block ticket -> loss.
#define D 256
#define TILE 64
#define EPS 1e-8f

typedef __attribute__((ext_vector_type(8))) short bf16x8;
typedef __attribute__((ext_vector_type(4))) float f32x4;

__device__ __forceinline__ void pair_decode(int p, int& ta, int& tb) {
  if (p < 4)      { ta = 0; tb = p; }
  else if (p < 7) { ta = 1; tb = p - 3; }
  else if (p < 9) { ta = 2; tb = p - 5; }
  else            { ta = 3; tb = 3; }
}

// swizzled short-index into Xt[col][64 rows] (row-stride 64 shorts = 128 B).
// XOR bits 3..5 of row with g(col): b128 frag reads ~2-way, b64 writes 4-way.
__device__ __forceinline__ int swz(int col, int r) {
  int g = ((col >> 2) & 7) ^ ((col & 3) << 1);
  return col * 64 + (r ^ (g << 3));
}

// round-to-nearest-even fp32 -> bf16 (truncation would bias S)
__device__ __forceinline__ unsigned short rne_bf16(float f) {
  unsigned u = __float_as_uint(f);
  return (unsigned short)((u + 0x7fffu + ((u >> 16) & 1u)) >> 16);
}

// ---------------------------------------------------------------------------
// Kernel 1: row inverse norms (one wave per row) + zero ctrl words.
// ---------------------------------------------------------------------------
__global__ __launch_bounds__(256) void k_prep(
    const float* __restrict__ x, float* __restrict__ inv,
    float* __restrict__ ctrl, int N) {
  if (blockIdx.x == 0 && threadIdx.x < 16) ctrl[threadIdx.x] = 0.0f;
  int wave = (blockIdx.x * blockDim.x + threadIdx.x) >> 6;
  int lane = threadIdx.x & 63;
  if (wave >= N) return;
  const float4 v = reinterpret_cast<const float4*>(x + (size_t)wave * D)[lane];
  float s = v.x * v.x + v.y * v.y + v.z * v.z + v.w * v.w;
  #pragma unroll
  for (int o = 32; o > 0; o >>= 1) s += __shfl_xor(s, o);
  if (lane == 0) inv[wave] = 1.0f / fmaxf(sqrtf(s), EPS);
}

// ---------------------------------------------------------------------------
// Kernel 2: Gram tiles, balanced. 256 blocks x 512 threads.
//   bid <  192: off-diag pair op[bid>>5], chunk = bid&31, 256 rows (4 sub)
//   bid >= 192: diag pair dp[(bid-192)>>4], chunk = &15, 512 rows (8 sub)
// Slab index = bid (16 KB each).
// ---------------------------------------------------------------------------
__global__ __launch_bounds__(512) void k_gram(
    const float* __restrict__ x, const float* __restrict__ inv,
    float* __restrict__ slabs) {
  const int bid = blockIdx.x;
  int p, row0, nsub;
  bool same;
  if (bid < 192) {
    const int op[6] = {1, 2, 3, 5, 6, 8};
    p = op[bid >> 5];
    row0 = (bid & 31) * 256;  nsub = 4;  same = false;
  } else {
    const int dp[4] = {0, 4, 7, 9};
    p = dp[(bid - 192) >> 4];
    row0 = ((bid - 192) & 15) * 512;  nsub = 8;  same = true;
  }
  int ta, tb; pair_decode(p, ta, tb);

  const int tid = threadIdx.x;
  const int w = tid >> 6, lane = tid & 63;

  __shared__ short X[2][128 * 64];  // double-buffered [col][row] bf16 tile

  // staging: 4 rows x 4 cols micro-transpose per task
  const int lcb = same ? 4 : 5;                 // log2(col-blocks)
  const int ntask = 16 << lcb;                  // 256 or 512
  const bool active = tid < ntask;
  const int c0 = (tid & ((1 << lcb) - 1)) << 2; // LDS col base
  const int r0 = (active ? (tid >> lcb) : 0) << 2;
  const int gc0 = (c0 < TILE) ? ta * TILE + c0 : tb * TILE + (c0 - TILE);

  // MFMA decomposition: wave w owns 16x32 of the 64x64 tile
  const int i0 = (w >> 1) << 4;                 // 0,16,32,48
  const int j0 = (w & 1) << 5;                  // 0,32
  const int lm = lane & 15, lk = lane >> 4;
  const int bbase = same ? 0 : 64;

  f32x4 zero = {0.f, 0.f, 0.f, 0.f};
  f32x4 acc[2] = {zero, zero};

  float4 pv[4]; float4 piv;
  if (active) {
    piv = *reinterpret_cast<const float4*>(&inv[row0 + r0]);
    const float* xb = x + (size_t)(row0 + r0) * D + gc0;
    #pragma unroll
    for (int jj = 0; jj < 4; ++jj)
      pv[jj] = *reinterpret_cast<const float4*>(xb + (size_t)jj * D);
  }

  for (int s = 0; s < nsub; ++s) {
    short* Xb = X[s & 1];
    if (active) {
      const float ivv[4] = {piv.x, piv.y, piv.z, piv.w};
      unsigned short hh[4][4];
      #pragma unroll
      for (int jj = 0; jj < 4; ++jj) {
        const float vv[4] = {pv[jj].x, pv[jj].y, pv[jj].z, pv[jj].w};
        #pragma unroll
        for (int cc = 0; cc < 4; ++cc)
          hh[jj][cc] = rne_bf16(vv[cc] * ivv[jj]);
      }
      #pragma unroll
      for (int cc = 0; cc < 4; ++cc)
        *reinterpret_cast<ushort4*>(&Xb[swz(c0 + cc, r0)]) =
            make_ushort4(hh[0][cc], hh[1][cc], hh[2][cc], hh[3][cc]);
      if (s + 1 < nsub) {                       // prefetch next sub-chunk
        const int nr0 = row0 + (s + 1) * 64 + r0;
        piv = *reinterpret_cast<const float4*>(&inv[nr0]);
        const float* xb = x + (size_t)nr0 * D + gc0;
        #pragma unroll
        for (int jj = 0; jj < 4; ++jj)
          pv[jj] = *reinterpret_cast<const float4*>(xb + (size_t)jj * D);
      }
    }
    __syncthreads();                            // one barrier per sub-chunk
    #pragma unroll
    for (int rr = 0; rr < 64; rr += 32) {
      const int rbase = rr + lk * 8;
      bf16x8 A  = *reinterpret_cast<const bf16x8*>(&Xb[swz(i0 + lm, rbase)]);
      bf16x8 B0 = *reinterpret_cast<const bf16x8*>(&Xb[swz(bbase + j0 + lm, rbase)]);
      bf16x8 B1 = *reinterpret_cast<const bf16x8*>(&Xb[swz(bbase + j0 + 16 + lm, rbase)]);
      acc[0] = __builtin_amdgcn_mfma_f32_16x16x32_bf16(A, B0, acc[0], 0, 0, 0);
      acc[1] = __builtin_amdgcn_mfma_f32_16x16x32_bf16(A, B1, acc[1], 0, 0, 0);
    }
  }

  // slab store; C/D layout (m89): col = lane&15, row = (lane>>4)*4 + reg
  float* slab = slabs + (size_t)bid * (TILE * TILE);
  #pragma unroll
  for (int jt = 0; jt < 2; ++jt)
    #pragma unroll
    for (int rg = 0; rg < 4; ++rg)
      slab[(i0 + lk * 4 + rg) * TILE + (j0 + jt * 16 + lm)] = acc[jt][rg];
}

// ---------------------------------------------------------------------------
// Kernel 3: reduce. 160 blocks x 256 threads; one G element per thread:
// sum this pair's chunk partials (32 off-diag / 16 diag, coalesced),
// weight, square, block-reduce, atomicAdd(S), last-block ticket -> loss.
// ---------------------------------------------------------------------------
__global__ __launch_bounds__(256) void k_reduce(
    const float* __restrict__ slabs, float* __restrict__ S,
    unsigned int* __restrict__ cnt, float* __restrict__ out,
    int N, int nblocks) {
  const int g = blockIdx.x * 256 + threadIdx.x;
  const int p = g >> 12;                        // pair 0..9
  const int e = g & 4095;                       // element in 64x64 tile
  // slab base per pair (off-diag pairs occupy slabs 0..191, diag 192..255)
  const int base_tbl[10] = {192, 0, 32, 64, 208, 96, 128, 224, 160, 240};
  const bool diag = (p == 0) | (p == 4) | (p == 7) | (p == 9);
  const int nc = diag ? 16 : 32;
  const float* base = slabs + (size_t)base_tbl[p] * (TILE * TILE) + e;
  float tot = 0.f;
  #pragma unroll 8
  for (int c = 0; c < nc; ++c) tot += base[(size_t)c * (TILE * TILE)];
  float part = (diag ? 1.f : 2.f) * tot * tot;
  #pragma unroll
  for (int o = 32; o > 0; o >>= 1) part += __shfl_xor(part, o);
  __shared__ float red[4];
  int lane = threadIdx.x & 63, w = threadIdx.x >> 6;
  if (lane == 0) red[w] = part;
  __syncthreads();
  if (threadIdx.x == 0) {
    float blk = red[0] + red[1] + red[2] + red[3];
    atomicAdd(S, blk);
    __threadfence();
    unsigned int old = atomicAdd(cnt, 1u);
    if (old == (unsigned int)(nblocks - 1)) {
      float Sv = __hip_atomic_load(S, __ATOMIC_RELAXED,
                                   __HIP_MEMORY_SCOPE_AGENT);
      float nf = (float)N;
      out[0] = (Sv - nf) / (nf * nf - nf);
    }
  }
}

extern "C" void kernel_launch(void* const* d_in, const int* in_sizes, int n_in,
                              void* d_out, int out_size, void* d_ws, size_t ws_size,
                              hipStream_t stream) {
  const float* x = (const float*)d_in[0];
  float* out = (float*)d_out;
  const int N = in_sizes[0] / D;       // 8192

  // ws layout (floats): inv[N] | ctrl[64] (S, cnt) | slabs[256*4096]
  float* inv = (float*)d_ws;
  float* ctrl = inv + N;
  float* S = ctrl;
  unsigned int* cnt = (unsigned int*)(ctrl + 1);
  float* slabs = ctrl + 64;

  k_prep<<<dim3(N / 4), dim3(256), 0, stream>>>(x, inv, ctrl, N);
  k_gram<<<dim3(256), dim3(512), 0, stream>>>(x, inv, slabs);
  const int nb = 10 * (TILE * TILE / 256);      // 160
  k_reduce<<<dim3(nb), dim3(256), 0, stream>>>(slabs, S, cnt, out, N, nb);
}